// Round 1
// baseline (786.455 us; speedup 1.0000x reference)
//
#include <hip/hip_runtime.h>
#include <hip/hip_bf16.h>

// GCN: x1 = relu(scatter(norm * (X@W1)[src] -> dst) + b1)
//      x2 = relu(scatter(norm * (x1@W2)[src] -> dst) + b2)
//      out = meanpool_by_graph(x2) @ Wlin + blin
constexpr int NN = 100000;   // nodes
constexpr int NE = 1600000;  // edges
constexpr int NG = 512;      // graphs
constexpr int F  = 128;      // feature dim (in == hidden)

// ---------------- degree / CSR build ----------------

__global__ void count_edges(const int* __restrict__ ei, int* __restrict__ counts) {
    int e = blockIdx.x * blockDim.x + threadIdx.x;
    if (e < NE) atomicAdd(&counts[ei[NE + e]], 1);
}

__global__ void compute_dis(const int* __restrict__ counts, float* __restrict__ dis) {
    int i = blockIdx.x * blockDim.x + threadIdx.x;
    if (i < NN) dis[i] = rsqrtf((float)(counts[i] + 1));  // +1 self-loop; deg >= 1 always
}

// exclusive scan of counts -> offs (3-kernel standard scan)
__global__ void scan1(const int* __restrict__ counts, int* __restrict__ offs,
                      int* __restrict__ blockSums, int n) {
    __shared__ int tmp[1024];
    int i = blockIdx.x * 1024 + threadIdx.x;
    int v = (i < n) ? counts[i] : 0;
    tmp[threadIdx.x] = v;
    __syncthreads();
    for (int d = 1; d < 1024; d <<= 1) {
        int t = (threadIdx.x >= d) ? tmp[threadIdx.x - d] : 0;
        __syncthreads();
        tmp[threadIdx.x] += t;
        __syncthreads();
    }
    int inc = tmp[threadIdx.x];
    if (i < n) offs[i] = inc - v;  // exclusive
    if (threadIdx.x == 1023) blockSums[blockIdx.x] = inc;
}

__global__ void scan2(int* __restrict__ blockSums, int nb) {
    if (threadIdx.x == 0) {
        int acc = 0;
        for (int b = 0; b < nb; b++) { int v = blockSums[b]; blockSums[b] = acc; acc += v; }
    }
}

__global__ void scan3(int* __restrict__ offs, const int* __restrict__ blockSums,
                      int* __restrict__ cursor, int n) {
    int i = blockIdx.x * blockDim.x + threadIdx.x;
    if (i < n) {
        int v = offs[i] + blockSums[i >> 10];
        offs[i] = v;
        cursor[i] = v;
    }
    if (i == n) offs[n] = NE;
}

__global__ void fill_csr(const int* __restrict__ ei, const float* __restrict__ dis,
                         int* __restrict__ cursor, int* __restrict__ csr_src,
                         float* __restrict__ csr_norm) {
    int e = blockIdx.x * blockDim.x + threadIdx.x;
    if (e < NE) {
        int s = ei[e], d = ei[NE + e];
        int pos = atomicAdd(&cursor[d], 1);
        csr_src[pos]  = s;
        csr_norm[pos] = dis[s] * dis[d];
    }
}

// ---------------- fp32 GEMM: H[M,128] = X[M,128] @ W[128,128] ----------------
// block = 256 threads, tile = 128 rows x 128 cols, thread = 8 rows x 8 cols.
__global__ __launch_bounds__(256) void gemm128(const float* __restrict__ X,
                                               const float* __restrict__ W,
                                               float* __restrict__ H, int M) {
    __shared__ float sW[128 * 128];   // [k][j], 64 KB
    __shared__ float sX[128 * 132];   // [r][k], stride 132 floats (33 f4) to dodge conflicts
    const int tid = threadIdx.x;
    {
        const float4* W4 = (const float4*)W;
        float4* sW4 = (float4*)sW;
        #pragma unroll
        for (int i = 0; i < 16; i++) sW4[tid + 256 * i] = W4[tid + 256 * i];
    }
    const int row0 = blockIdx.x * 128;
    {
        const float4* X4 = (const float4*)X;
        float4* sX4 = (float4*)sX;
        #pragma unroll
        for (int i = 0; i < 16; i++) {
            int idx = tid + 256 * i;       // 0..4095
            int r = idx >> 5, c = idx & 31;
            float4 v = make_float4(0.f, 0.f, 0.f, 0.f);
            if (row0 + r < M) v = X4[(size_t)(row0 + r) * 32 + c];
            sX4[r * 33 + c] = v;
        }
    }
    __syncthreads();

    const int tx = tid & 15;       // col group: cols tx*4..+3 and tx*4+64..+67
    const int ty = tid >> 4;       // row base: rows ty + 16*r
    float4 a0[8], a1[8];
    #pragma unroll
    for (int r = 0; r < 8; r++) {
        a0[r] = make_float4(0.f, 0.f, 0.f, 0.f);
        a1[r] = make_float4(0.f, 0.f, 0.f, 0.f);
    }
    const float4* sW4 = (const float4*)sW;
    const float4* sX4 = (const float4*)sX;
    #pragma unroll 2
    for (int k4 = 0; k4 < 32; k4++) {
        float4 xs[8];
        #pragma unroll
        for (int r = 0; r < 8; r++) xs[r] = sX4[(ty + (r << 4)) * 33 + k4];
        #pragma unroll
        for (int kk = 0; kk < 4; kk++) {
            float4 w0 = sW4[((k4 << 2) + kk) * 32 + tx];
            float4 w1 = sW4[((k4 << 2) + kk) * 32 + tx + 16];
            #pragma unroll
            for (int r = 0; r < 8; r++) {
                float xv = kk == 0 ? xs[r].x : kk == 1 ? xs[r].y : kk == 2 ? xs[r].z : xs[r].w;
                a0[r].x = fmaf(xv, w0.x, a0[r].x);
                a0[r].y = fmaf(xv, w0.y, a0[r].y);
                a0[r].z = fmaf(xv, w0.z, a0[r].z);
                a0[r].w = fmaf(xv, w0.w, a0[r].w);
                a1[r].x = fmaf(xv, w1.x, a1[r].x);
                a1[r].y = fmaf(xv, w1.y, a1[r].y);
                a1[r].z = fmaf(xv, w1.z, a1[r].z);
                a1[r].w = fmaf(xv, w1.w, a1[r].w);
            }
        }
    }
    #pragma unroll
    for (int r = 0; r < 8; r++) {
        int row = row0 + ty + (r << 4);
        if (row < M) {
            float4* H4 = (float4*)(H + (size_t)row * 128);
            H4[tx]      = a0[r];
            H4[tx + 16] = a1[r];
        }
    }
}

// ---------------- per-node gather aggregation + bias + relu ----------------
__global__ __launch_bounds__(128) void aggregate(const float* __restrict__ h,
                                                 const int* __restrict__ offs,
                                                 const int* __restrict__ csr_src,
                                                 const float* __restrict__ csr_norm,
                                                 const float* __restrict__ dis,
                                                 const float* __restrict__ bias,
                                                 float* __restrict__ out) {
    int i = blockIdx.x;
    int f = threadIdx.x;
    float di = dis[i];
    float acc = h[(size_t)i * F + f] * (di * di);  // self-loop
    int s = offs[i], e = offs[i + 1];
    for (int t = s; t < e; t++) {
        int sr = csr_src[t];
        float nm = csr_norm[t];
        acc = fmaf(h[(size_t)sr * F + f], nm, acc);
    }
    float v = acc + bias[f];
    out[(size_t)i * F + f] = v > 0.f ? v : 0.f;
}

// ---------------- fused mean-pool (sorted batch, binary search) + linear ----------------
__global__ __launch_bounds__(128) void pool_linear(const float* __restrict__ x,
                                                   const int* __restrict__ batch,
                                                   const float* __restrict__ Wlin,
                                                   const float* __restrict__ blin,
                                                   float* __restrict__ out, int n) {
    int g = blockIdx.x;   // graph id
    int f = threadIdx.x;  // feature
    __shared__ int se[2];
    if (threadIdx.x < 2) {
        int target = g + threadIdx.x;
        int lo = 0, hi = n;
        while (lo < hi) {
            int mid = (lo + hi) >> 1;
            if (batch[mid] < target) lo = mid + 1; else hi = mid;
        }
        se[threadIdx.x] = lo;
    }
    __syncthreads();
    int s = se[0], e = se[1];
    float acc = 0.f;
    for (int i = s; i < e; i++) acc += x[(size_t)i * F + f];
    float cnt = (float)((e - s) > 0 ? (e - s) : 1);
    float p = acc / cnt;
    float v0 = p * Wlin[f * 2 + 0];
    float v1 = p * Wlin[f * 2 + 1];
    #pragma unroll
    for (int o = 32; o > 0; o >>= 1) {
        v0 += __shfl_xor(v0, o);
        v1 += __shfl_xor(v1, o);
    }
    __shared__ float red[4];
    int wid = threadIdx.x >> 6;
    if ((threadIdx.x & 63) == 0) { red[wid * 2] = v0; red[wid * 2 + 1] = v1; }
    __syncthreads();
    if (threadIdx.x == 0) {
        out[g * 2 + 0] = red[0] + red[2] + blin[0];
        out[g * 2 + 1] = red[1] + red[3] + blin[1];
    }
}

extern "C" void kernel_launch(void* const* d_in, const int* in_sizes, int n_in,
                              void* d_out, int out_size, void* d_ws, size_t ws_size,
                              hipStream_t stream) {
    const float* X     = (const float*)d_in[0];
    const int*   ei    = (const int*)d_in[1];
    const int*   batch = (const int*)d_in[2];
    const float* W1    = (const float*)d_in[3];
    const float* b1    = (const float*)d_in[4];
    const float* W2    = (const float*)d_in[5];
    const float* b2    = (const float*)d_in[6];
    const float* Wlin  = (const float*)d_in[7];
    const float* blin  = (const float*)d_in[8];
    float* out = (float*)d_out;

    char* p = (char*)d_ws;
    auto alloc = [&](size_t bytes) -> char* {
        char* r = p;
        p += (bytes + 255) & ~size_t(255);
        return r;
    };
    int*   counts    = (int*)alloc((size_t)NN * 4);
    int*   offs      = (int*)alloc((size_t)(NN + 1) * 4);
    int*   cursor    = (int*)alloc((size_t)NN * 4);
    int*   blockSums = (int*)alloc(1024 * 4);
    float* dis       = (float*)alloc((size_t)NN * 4);
    int*   csr_src   = (int*)alloc((size_t)NE * 4);
    float* csr_norm  = (float*)alloc((size_t)NE * 4);
    float* bufA      = (float*)alloc((size_t)NN * F * 4);
    float* bufB      = (float*)alloc((size_t)NN * F * 4);

    const int nscan = (NN + 1023) / 1024;

    hipMemsetAsync(counts, 0, (size_t)NN * 4, stream);
    count_edges<<<(NE + 255) / 256, 256, 0, stream>>>(ei, counts);
    compute_dis<<<(NN + 255) / 256, 256, 0, stream>>>(counts, dis);
    scan1<<<nscan, 1024, 0, stream>>>(counts, offs, blockSums, NN);
    scan2<<<1, 64, 0, stream>>>(blockSums, nscan);
    scan3<<<(NN + 1 + 255) / 256, 256, 0, stream>>>(offs, blockSums, cursor, NN);
    fill_csr<<<(NE + 255) / 256, 256, 0, stream>>>(ei, dis, cursor, csr_src, csr_norm);

    gemm128<<<(NN + 127) / 128, 256, 0, stream>>>(X, W1, bufA, NN);
    aggregate<<<NN, 128, 0, stream>>>(bufA, offs, csr_src, csr_norm, dis, b1, bufB);
    gemm128<<<(NN + 127) / 128, 256, 0, stream>>>(bufB, W2, bufA, NN);
    aggregate<<<NN, 128, 0, stream>>>(bufA, offs, csr_src, csr_norm, dis, b2, bufB);
    pool_linear<<<NG, 128, 0, stream>>>(bufB, batch, Wlin, blin, out, NN);
}

// Round 2
// 625.341 us; speedup vs baseline: 1.2576x; 1.2576x over previous
//
#include <hip/hip_runtime.h>
#include <hip/hip_bf16.h>
#include <hip/hip_fp16.h>

// GCN: x1 = relu(scatter(norm * (X@W1)[src] -> dst) + b1)
//      x2 = relu(scatter(norm * (x1@W2)[src] -> dst) + b2)
//      out = meanpool_by_graph(x2) @ Wlin + blin
// fp16 h buffers (halve gather bytes), fp32 accumulate everywhere.
constexpr int NN = 100000;   // nodes
constexpr int NE = 1600000;  // edges
constexpr int NG = 512;      // graphs
constexpr int F  = 128;      // feature dim (in == hidden)

typedef _Float16 f16;
typedef f16 f16x2 __attribute__((ext_vector_type(2)));
typedef f16 f16x4 __attribute__((ext_vector_type(4)));
typedef f16 f16x8 __attribute__((ext_vector_type(8)));
typedef float f32x4 __attribute__((ext_vector_type(4)));

// ---------------- degree / CSR build ----------------

__global__ void count_edges(const int* __restrict__ ei, int* __restrict__ counts) {
    int e = blockIdx.x * blockDim.x + threadIdx.x;
    if (e < NE) atomicAdd(&counts[ei[NE + e]], 1);
}

__global__ void compute_dis(const int* __restrict__ counts, float* __restrict__ dis) {
    int i = blockIdx.x * blockDim.x + threadIdx.x;
    if (i < NN) dis[i] = rsqrtf((float)(counts[i] + 1));  // +1 self-loop; deg >= 1 always
}

__global__ void scan1(const int* __restrict__ counts, int* __restrict__ offs,
                      int* __restrict__ blockSums, int n) {
    __shared__ int tmp[1024];
    int i = blockIdx.x * 1024 + threadIdx.x;
    int v = (i < n) ? counts[i] : 0;
    tmp[threadIdx.x] = v;
    __syncthreads();
    for (int d = 1; d < 1024; d <<= 1) {
        int t = (threadIdx.x >= d) ? tmp[threadIdx.x - d] : 0;
        __syncthreads();
        tmp[threadIdx.x] += t;
        __syncthreads();
    }
    int inc = tmp[threadIdx.x];
    if (i < n) offs[i] = inc - v;  // exclusive
    if (threadIdx.x == 1023) blockSums[blockIdx.x] = inc;
}

__global__ void scan2(int* __restrict__ blockSums, int nb) {
    if (threadIdx.x == 0) {
        int acc = 0;
        for (int b = 0; b < nb; b++) { int v = blockSums[b]; blockSums[b] = acc; acc += v; }
    }
}

__global__ void scan3(int* __restrict__ offs, const int* __restrict__ blockSums,
                      int* __restrict__ cursor, int n) {
    int i = blockIdx.x * blockDim.x + threadIdx.x;
    if (i < n) {
        int v = offs[i] + blockSums[i >> 10];
        offs[i] = v;
        cursor[i] = v;
    }
    if (i == n) offs[n] = NE;
}

__global__ void fill_csr(const int* __restrict__ ei, const float* __restrict__ dis,
                         int* __restrict__ cursor, int* __restrict__ csr_src,
                         float* __restrict__ csr_norm) {
    int e = blockIdx.x * blockDim.x + threadIdx.x;
    if (e < NE) {
        int s = ei[e], d = ei[NE + e];
        int pos = atomicAdd(&cursor[d], 1);
        csr_src[pos]  = s;
        csr_norm[pos] = dis[s] * dis[d];
    }
}

// ---------------- W prep: fp32 [k][n] -> fp16 transposed [n][k] ----------------
__global__ void prep_w(const float* __restrict__ W1, const float* __restrict__ W2,
                       f16* __restrict__ WT1, f16* __restrict__ WT2) {
    int idx = blockIdx.x * blockDim.x + threadIdx.x;
    if (idx < 128 * 128) {
        int n = idx >> 7, k = idx & 127;
        WT1[idx] = (f16)W1[k * 128 + n];
        WT2[idx] = (f16)W2[k * 128 + n];
    }
}

// ---------------- MFMA fp16 GEMM: H[M,128] = X[M,128] @ W[128,128] ----------------
// block = 256 threads (4 waves); BM=128; wave w does rows w*32..w*32+31, all 128 cols.
// LDS rows padded to 136 halves (272 B stride: 2-way bank aliasing = free, 16 B aligned).
template<bool IN_HALF>
__global__ __launch_bounds__(256) void gemm_mfma(const void* __restrict__ Xv,
                                                 const f16* __restrict__ WT,  // [n][k] fp16
                                                 f16* __restrict__ H, int M) {
    __shared__ f16 sX[128 * 136];
    __shared__ f16 sW[128 * 136];
    const int tid = threadIdx.x;
    const int row0 = blockIdx.x * 128;
    {   // stage W^T: [n][k]
        const f16x8* Wg = (const f16x8*)WT;
        #pragma unroll
        for (int i = 0; i < 8; i++) {
            int idx = tid + 256 * i;       // 2048 chunks of 8 halves
            int n = idx >> 4, kc = idx & 15;
            *(f16x8*)&sX[0] = *(f16x8*)&sX[0]; // no-op to keep layout symmetric (optimized out)
            *(f16x8*)&sW[n * 136 + kc * 8] = Wg[idx];
        }
    }
    if (IN_HALF) {
        const f16x8* Xg = (const f16x8*)Xv;
        #pragma unroll
        for (int i = 0; i < 8; i++) {
            int idx = tid + 256 * i;
            int r = idx >> 4, kc = idx & 15;
            f16x8 v = {};
            if (row0 + r < M) v = Xg[(size_t)(row0 + r) * 16 + kc];
            *(f16x8*)&sX[r * 136 + kc * 8] = v;
        }
    } else {
        const float4* Xg = (const float4*)Xv;
        #pragma unroll
        for (int i = 0; i < 16; i++) {
            int idx = tid + 256 * i;       // 4096 chunks of 4 floats
            int r = idx >> 5, c4 = idx & 31;
            float4 v = make_float4(0.f, 0.f, 0.f, 0.f);
            if (row0 + r < M) v = Xg[(size_t)(row0 + r) * 32 + c4];
            f16x4 hv = {(f16)v.x, (f16)v.y, (f16)v.z, (f16)v.w};
            *(f16x4*)&sX[r * 136 + c4 * 4] = hv;
        }
    }
    __syncthreads();

    const int wid = tid >> 6;
    const int lane = tid & 63;
    const int wrow = wid * 32;
    const int lr = lane & 15;            // row (A) / col (B) within 16
    const int lk = (lane >> 4) * 8;      // k base
    f32x4 acc[2][8] = {};
    #pragma unroll
    for (int ks = 0; ks < 4; ks++) {
        f16x8 a[2], b[8];
        #pragma unroll
        for (int mf = 0; mf < 2; mf++)
            a[mf] = *(const f16x8*)&sX[(wrow + mf * 16 + lr) * 136 + ks * 32 + lk];
        #pragma unroll
        for (int nf = 0; nf < 8; nf++)
            b[nf] = *(const f16x8*)&sW[(nf * 16 + lr) * 136 + ks * 32 + lk];
        #pragma unroll
        for (int mf = 0; mf < 2; mf++)
            #pragma unroll
            for (int nf = 0; nf < 8; nf++)
                acc[mf][nf] = __builtin_amdgcn_mfma_f32_16x16x32_f16(a[mf], b[nf], acc[mf][nf], 0, 0, 0);
    }
    // C layout: col = lane&15, row = (lane>>4)*4 + reg
    const int crow = (lane >> 4) * 4;
    #pragma unroll
    for (int mf = 0; mf < 2; mf++) {
        #pragma unroll
        for (int reg = 0; reg < 4; reg++) {
            int row = row0 + wrow + mf * 16 + crow + reg;
            if (row < M) {
                #pragma unroll
                for (int nf = 0; nf < 8; nf++)
                    H[(size_t)row * 128 + nf * 16 + lr] = (f16)acc[mf][nf][reg];
            }
        }
    }
}

// ---------------- per-node gather aggregation + bias + relu (fp16 h) ----------------
// 1 wave per node, 4 nodes per 256-thread block; lane owns features [2*lane, 2*lane+1].
__global__ __launch_bounds__(256) void aggregate16(const f16* __restrict__ h,
                                                   const int* __restrict__ offs,
                                                   const int* __restrict__ csr_src,
                                                   const float* __restrict__ csr_norm,
                                                   const float* __restrict__ dis,
                                                   const float* __restrict__ bias,
                                                   f16* __restrict__ out, int n) {
    int i = blockIdx.x * 4 + (threadIdx.x >> 6);
    if (i >= n) return;
    int lane = threadIdx.x & 63;
    const f16x2* h2 = (const f16x2*)h;
    float di = dis[i];
    float sc = di * di;
    f16x2 hv = h2[(size_t)i * 64 + lane];
    float a0 = (float)hv[0] * sc, a1 = (float)hv[1] * sc;  // self-loop
    int s = offs[i], e = offs[i + 1];
    for (int t = s; t < e; t++) {
        int sr = csr_src[t];
        float nm = csr_norm[t];
        f16x2 v = h2[(size_t)sr * 64 + lane];
        a0 = fmaf((float)v[0], nm, a0);
        a1 = fmaf((float)v[1], nm, a1);
    }
    float2 bb = *(const float2*)&bias[lane * 2];
    a0 += bb.x; a1 += bb.y;
    a0 = a0 > 0.f ? a0 : 0.f;
    a1 = a1 > 0.f ? a1 : 0.f;
    f16x2 o = {(f16)a0, (f16)a1};
    ((f16x2*)out)[(size_t)i * 64 + lane] = o;
}

// ---------------- fused mean-pool (sorted batch, binary search) + linear ----------------
__global__ __launch_bounds__(128) void pool_linear(const f16* __restrict__ x,
                                                   const int* __restrict__ batch,
                                                   const float* __restrict__ Wlin,
                                                   const float* __restrict__ blin,
                                                   float* __restrict__ out, int n) {
    int g = blockIdx.x;   // graph id
    int f = threadIdx.x;  // feature
    __shared__ int se[2];
    if (threadIdx.x < 2) {
        int target = g + threadIdx.x;
        int lo = 0, hi = n;
        while (lo < hi) {
            int mid = (lo + hi) >> 1;
            if (batch[mid] < target) lo = mid + 1; else hi = mid;
        }
        se[threadIdx.x] = lo;
    }
    __syncthreads();
    int s = se[0], e = se[1];
    float acc = 0.f;
    for (int i = s; i < e; i++) acc += (float)x[(size_t)i * F + f];
    float cnt = (float)((e - s) > 0 ? (e - s) : 1);
    float p = acc / cnt;
    float v0 = p * Wlin[f * 2 + 0];
    float v1 = p * Wlin[f * 2 + 1];
    #pragma unroll
    for (int o = 32; o > 0; o >>= 1) {
        v0 += __shfl_xor(v0, o);
        v1 += __shfl_xor(v1, o);
    }
    __shared__ float red[4];
    int wid = threadIdx.x >> 6;
    if ((threadIdx.x & 63) == 0) { red[wid * 2] = v0; red[wid * 2 + 1] = v1; }
    __syncthreads();
    if (threadIdx.x == 0) {
        out[g * 2 + 0] = red[0] + red[2] + blin[0];
        out[g * 2 + 1] = red[1] + red[3] + blin[1];
    }
}

extern "C" void kernel_launch(void* const* d_in, const int* in_sizes, int n_in,
                              void* d_out, int out_size, void* d_ws, size_t ws_size,
                              hipStream_t stream) {
    const float* X     = (const float*)d_in[0];
    const int*   ei    = (const int*)d_in[1];
    const int*   batch = (const int*)d_in[2];
    const float* W1    = (const float*)d_in[3];
    const float* b1    = (const float*)d_in[4];
    const float* W2    = (const float*)d_in[5];
    const float* b2    = (const float*)d_in[6];
    const float* Wlin  = (const float*)d_in[7];
    const float* blin  = (const float*)d_in[8];
    float* out = (float*)d_out;

    char* p = (char*)d_ws;
    auto alloc = [&](size_t bytes) -> char* {
        char* r = p;
        p += (bytes + 255) & ~size_t(255);
        return r;
    };
    int*   counts    = (int*)alloc((size_t)NN * 4);
    int*   offs      = (int*)alloc((size_t)(NN + 1) * 4);
    int*   cursor    = (int*)alloc((size_t)NN * 4);
    int*   blockSums = (int*)alloc(1024 * 4);
    float* dis       = (float*)alloc((size_t)NN * 4);
    int*   csr_src   = (int*)alloc((size_t)NE * 4);
    float* csr_norm  = (float*)alloc((size_t)NE * 4);
    f16*   WT1       = (f16*)alloc((size_t)128 * 128 * 2);
    f16*   WT2       = (f16*)alloc((size_t)128 * 128 * 2);
    f16*   bufA      = (f16*)alloc((size_t)NN * F * 2);
    f16*   bufB      = (f16*)alloc((size_t)NN * F * 2);

    const int nscan = (NN + 1023) / 1024;

    hipMemsetAsync(counts, 0, (size_t)NN * 4, stream);
    count_edges<<<(NE + 255) / 256, 256, 0, stream>>>(ei, counts);
    compute_dis<<<(NN + 255) / 256, 256, 0, stream>>>(counts, dis);
    scan1<<<nscan, 1024, 0, stream>>>(counts, offs, blockSums, NN);
    scan2<<<1, 64, 0, stream>>>(blockSums, nscan);
    scan3<<<(NN + 1 + 255) / 256, 256, 0, stream>>>(offs, blockSums, cursor, NN);
    fill_csr<<<(NE + 255) / 256, 256, 0, stream>>>(ei, dis, cursor, csr_src, csr_norm);
    prep_w<<<64, 256, 0, stream>>>(W1, W2, WT1, WT2);

    gemm_mfma<false><<<(NN + 127) / 128, 256, 0, stream>>>(X, WT1, bufA, NN);
    aggregate16<<<(NN + 3) / 4, 256, 0, stream>>>(bufA, offs, csr_src, csr_norm, dis, b1, bufB, NN);
    gemm_mfma<true><<<(NN + 127) / 128, 256, 0, stream>>>(bufB, WT2, bufA, NN);
    aggregate16<<<(NN + 3) / 4, 256, 0, stream>>>(bufA, offs, csr_src, csr_norm, dis, b2, bufB, NN);
    pool_linear<<<NG, 128, 0, stream>>>(bufB, batch, Wlin, blin, out, NN);
}

// Round 3
// 451.447 us; speedup vs baseline: 1.7421x; 1.3852x over previous
//
#include <hip/hip_runtime.h>
#include <hip/hip_bf16.h>
#include <hip/hip_fp16.h>

// GCN: x1 = relu(scatter(norm * (X@W1)[src] -> dst) + b1)
//      x2 = relu(scatter(norm * (x1@W2)[src] -> dst) + b2)
//      out = meanpool_by_graph(x2) @ Wlin + blin
// Factored norm: out[d] = dis[d]*(sum_{s in N(d)} h'[s] + h'[d]) + b,
// where h' = (X@W) row-scaled by dis (done in GEMM epilogue, fp16 stored).
constexpr int NN = 100000;   // nodes
constexpr int NE = 1600000;  // edges
constexpr int NG = 512;      // graphs
constexpr int F  = 128;      // feature dim (in == hidden)

typedef _Float16 f16;
typedef f16 f16x2 __attribute__((ext_vector_type(2)));
typedef f16 f16x4 __attribute__((ext_vector_type(4)));
typedef f16 f16x8 __attribute__((ext_vector_type(8)));
typedef float f32x4 __attribute__((ext_vector_type(4)));

// ---------------- degree / CSR build ----------------

__global__ void count_edges(const int* __restrict__ ei, int* __restrict__ counts) {
    int e = blockIdx.x * blockDim.x + threadIdx.x;
    if (e < NE) atomicAdd(&counts[ei[NE + e]], 1);
}

__global__ void compute_dis(const int* __restrict__ counts, float* __restrict__ dis) {
    int i = blockIdx.x * blockDim.x + threadIdx.x;
    if (i < NN) dis[i] = rsqrtf((float)(counts[i] + 1));  // +1 self-loop; deg >= 1 always
}

__global__ void scan1(const int* __restrict__ counts, int* __restrict__ offs,
                      int* __restrict__ blockSums, int n) {
    __shared__ int tmp[1024];
    int i = blockIdx.x * 1024 + threadIdx.x;
    int v = (i < n) ? counts[i] : 0;
    tmp[threadIdx.x] = v;
    __syncthreads();
    for (int d = 1; d < 1024; d <<= 1) {
        int t = (threadIdx.x >= d) ? tmp[threadIdx.x - d] : 0;
        __syncthreads();
        tmp[threadIdx.x] += t;
        __syncthreads();
    }
    int inc = tmp[threadIdx.x];
    if (i < n) offs[i] = inc - v;  // exclusive
    if (threadIdx.x == 1023) blockSums[blockIdx.x] = inc;
}

// one-block exclusive scan over <=128 block sums (was serial: ~20us of dependent loads)
__global__ void scan2(int* __restrict__ blockSums, int nb) {
    __shared__ int tmp[128];
    int t = threadIdx.x;
    int v = (t < nb) ? blockSums[t] : 0;
    tmp[t] = v;
    __syncthreads();
    for (int d = 1; d < 128; d <<= 1) {
        int x = (t >= d) ? tmp[t - d] : 0;
        __syncthreads();
        tmp[t] += x;
        __syncthreads();
    }
    if (t < nb) blockSums[t] = tmp[t] - v;  // exclusive
}

__global__ void scan3(int* __restrict__ offs, const int* __restrict__ blockSums,
                      int* __restrict__ cursor, int n) {
    int i = blockIdx.x * blockDim.x + threadIdx.x;
    if (i < n) {
        int v = offs[i] + blockSums[i >> 10];
        offs[i] = v;
        cursor[i] = v;
    }
    if (i == n) offs[n] = NE;
}

__global__ void fill_csr(const int* __restrict__ ei, int* __restrict__ cursor,
                         int* __restrict__ csr_src) {
    int e = blockIdx.x * blockDim.x + threadIdx.x;
    if (e < NE) {
        int s = ei[e], d = ei[NE + e];
        int pos = atomicAdd(&cursor[d], 1);
        csr_src[pos] = s;
    }
}

// ---------------- W prep: fp32 [k][n] -> fp16 transposed [n][k] ----------------
__global__ void prep_w(const float* __restrict__ W1, const float* __restrict__ W2,
                       f16* __restrict__ WT1, f16* __restrict__ WT2) {
    int idx = blockIdx.x * blockDim.x + threadIdx.x;
    if (idx < 128 * 128) {
        int n = idx >> 7, k = idx & 127;
        WT1[idx] = (f16)W1[k * 128 + n];
        WT2[idx] = (f16)W2[k * 128 + n];
    }
}

// ---------------- MFMA fp16 GEMM: H[M,128] = (X[M,128] @ W[128,128]) * dis[row] ----------------
// block = 256 threads (4 waves); BM=128; wave w does rows w*32..w*32+31, all 128 cols.
// LDS rows padded to 136 halves (272 B stride: 2-way bank aliasing = free, 16 B aligned).
template<bool IN_HALF>
__global__ __launch_bounds__(256) void gemm_mfma(const void* __restrict__ Xv,
                                                 const f16* __restrict__ WT,  // [n][k] fp16
                                                 const float* __restrict__ dis,
                                                 f16* __restrict__ H, int M) {
    __shared__ f16 sX[128 * 136];
    __shared__ f16 sW[128 * 136];
    const int tid = threadIdx.x;
    const int row0 = blockIdx.x * 128;
    {   // stage W^T: [n][k]
        const f16x8* Wg = (const f16x8*)WT;
        #pragma unroll
        for (int i = 0; i < 8; i++) {
            int idx = tid + 256 * i;       // 2048 chunks of 8 halves
            int n = idx >> 4, kc = idx & 15;
            *(f16x8*)&sW[n * 136 + kc * 8] = Wg[idx];
        }
    }
    if (IN_HALF) {
        const f16x8* Xg = (const f16x8*)Xv;
        #pragma unroll
        for (int i = 0; i < 8; i++) {
            int idx = tid + 256 * i;
            int r = idx >> 4, kc = idx & 15;
            f16x8 v = {};
            if (row0 + r < M) v = Xg[(size_t)(row0 + r) * 16 + kc];
            *(f16x8*)&sX[r * 136 + kc * 8] = v;
        }
    } else {
        const float4* Xg = (const float4*)Xv;
        #pragma unroll
        for (int i = 0; i < 16; i++) {
            int idx = tid + 256 * i;       // 4096 chunks of 4 floats
            int r = idx >> 5, c4 = idx & 31;
            float4 v = make_float4(0.f, 0.f, 0.f, 0.f);
            if (row0 + r < M) v = Xg[(size_t)(row0 + r) * 32 + c4];
            f16x4 hv = {(f16)v.x, (f16)v.y, (f16)v.z, (f16)v.w};
            *(f16x4*)&sX[r * 136 + c4 * 4] = hv;
        }
    }
    __syncthreads();

    const int wid = tid >> 6;
    const int lane = tid & 63;
    const int wrow = wid * 32;
    const int lr = lane & 15;            // row (A) / col (B) within 16
    const int lk = (lane >> 4) * 8;      // k base
    f32x4 acc[2][8] = {};
    #pragma unroll
    for (int ks = 0; ks < 4; ks++) {
        f16x8 a[2], b[8];
        #pragma unroll
        for (int mf = 0; mf < 2; mf++)
            a[mf] = *(const f16x8*)&sX[(wrow + mf * 16 + lr) * 136 + ks * 32 + lk];
        #pragma unroll
        for (int nf = 0; nf < 8; nf++)
            b[nf] = *(const f16x8*)&sW[(nf * 16 + lr) * 136 + ks * 32 + lk];
        #pragma unroll
        for (int mf = 0; mf < 2; mf++)
            #pragma unroll
            for (int nf = 0; nf < 8; nf++)
                acc[mf][nf] = __builtin_amdgcn_mfma_f32_16x16x32_f16(a[mf], b[nf], acc[mf][nf], 0, 0, 0);
    }
    // C layout: col = lane&15, row = (lane>>4)*4 + reg
    const int crow = (lane >> 4) * 4;
    #pragma unroll
    for (int mf = 0; mf < 2; mf++) {
        #pragma unroll
        for (int reg = 0; reg < 4; reg++) {
            int row = row0 + wrow + mf * 16 + crow + reg;
            if (row < M) {
                float sc = dis[row];
                #pragma unroll
                for (int nf = 0; nf < 8; nf++)
                    H[(size_t)row * 128 + nf * 16 + lr] = (f16)(acc[mf][nf][reg] * sc);
            }
        }
    }
}

// ---------------- per-node gather row-sum + scale + bias + relu (fp16 h') ----------------
// 1 wave per node, 4 nodes per 256-thread block.
// Quarter-wave q (16 lanes) processes edges t = s+q, s+q+4, ... ; lane r reads
// row chunk r (f16x8, 16 B) -> full 256 B row per quarter. Unroll-2 => up to
// 8 independent row-gathers in flight per wave (latency/MLP fix).
__global__ __launch_bounds__(256) void aggregate16(const f16* __restrict__ h,
                                                   const int* __restrict__ offs,
                                                   const int* __restrict__ csr_src,
                                                   const float* __restrict__ dis,
                                                   const float* __restrict__ bias,
                                                   f16* __restrict__ out, int n) {
    int i = blockIdx.x * 4 + (threadIdx.x >> 6);
    if (i >= n) return;
    const int lane = threadIdx.x & 63;
    const int q = lane >> 4;      // quarter 0..3
    const int r = lane & 15;      // 16-byte chunk within row
    float acc[8] = {};
    if (q == 0) {  // self-loop: h'[i]
        f16x8 v = *(const f16x8*)(h + (size_t)i * F + r * 8);
        #pragma unroll
        for (int j = 0; j < 8; j++) acc[j] = (float)v[j];
    }
    const int s = offs[i], e = offs[i + 1];
    int t = s + q;
    for (; t + 4 < e; t += 8) {
        int sr0 = csr_src[t];
        int sr1 = csr_src[t + 4];
        f16x8 v0 = *(const f16x8*)(h + (size_t)sr0 * F + r * 8);
        f16x8 v1 = *(const f16x8*)(h + (size_t)sr1 * F + r * 8);
        #pragma unroll
        for (int j = 0; j < 8; j++) acc[j] += (float)v0[j] + (float)v1[j];
    }
    if (t < e) {
        int sr = csr_src[t];
        f16x8 v = *(const f16x8*)(h + (size_t)sr * F + r * 8);
        #pragma unroll
        for (int j = 0; j < 8; j++) acc[j] += (float)v[j];
    }
    // combine quarters: chunk r lives in lanes r, r+16, r+32, r+48
    #pragma unroll
    for (int j = 0; j < 8; j++) {
        acc[j] += __shfl_xor(acc[j], 16);
        acc[j] += __shfl_xor(acc[j], 32);
    }
    if (q == 0) {
        float di = dis[i];
        const float4* b4 = (const float4*)bias;
        float4 bb0 = b4[r * 2], bb1 = b4[r * 2 + 1];
        float bb[8] = {bb0.x, bb0.y, bb0.z, bb0.w, bb1.x, bb1.y, bb1.z, bb1.w};
        f16x8 o;
        #pragma unroll
        for (int j = 0; j < 8; j++) {
            float v = fmaf(acc[j], di, bb[j]);
            o[j] = (f16)(v > 0.f ? v : 0.f);
        }
        *(f16x8*)(out + (size_t)i * F + r * 8) = o;
    }
}

// ---------------- fused mean-pool (sorted batch, binary search) + linear ----------------
__global__ __launch_bounds__(128) void pool_linear(const f16* __restrict__ x,
                                                   const int* __restrict__ batch,
                                                   const float* __restrict__ Wlin,
                                                   const float* __restrict__ blin,
                                                   float* __restrict__ out, int n) {
    int g = blockIdx.x;   // graph id
    int f = threadIdx.x;  // feature
    __shared__ int se[2];
    if (threadIdx.x < 2) {
        int target = g + threadIdx.x;
        int lo = 0, hi = n;
        while (lo < hi) {
            int mid = (lo + hi) >> 1;
            if (batch[mid] < target) lo = mid + 1; else hi = mid;
        }
        se[threadIdx.x] = lo;
    }
    __syncthreads();
    int s = se[0], e = se[1];
    float acc = 0.f;
    for (int i = s; i < e; i++) acc += (float)x[(size_t)i * F + f];
    float cnt = (float)((e - s) > 0 ? (e - s) : 1);
    float p = acc / cnt;
    float v0 = p * Wlin[f * 2 + 0];
    float v1 = p * Wlin[f * 2 + 1];
    #pragma unroll
    for (int o = 32; o > 0; o >>= 1) {
        v0 += __shfl_xor(v0, o);
        v1 += __shfl_xor(v1, o);
    }
    __shared__ float red[4];
    int wid = threadIdx.x >> 6;
    if ((threadIdx.x & 63) == 0) { red[wid * 2] = v0; red[wid * 2 + 1] = v1; }
    __syncthreads();
    if (threadIdx.x == 0) {
        out[g * 2 + 0] = red[0] + red[2] + blin[0];
        out[g * 2 + 1] = red[1] + red[3] + blin[1];
    }
}

extern "C" void kernel_launch(void* const* d_in, const int* in_sizes, int n_in,
                              void* d_out, int out_size, void* d_ws, size_t ws_size,
                              hipStream_t stream) {
    const float* X     = (const float*)d_in[0];
    const int*   ei    = (const int*)d_in[1];
    const int*   batch = (const int*)d_in[2];
    const float* W1    = (const float*)d_in[3];
    const float* b1    = (const float*)d_in[4];
    const float* W2    = (const float*)d_in[5];
    const float* b2    = (const float*)d_in[6];
    const float* Wlin  = (const float*)d_in[7];
    const float* blin  = (const float*)d_in[8];
    float* out = (float*)d_out;

    char* p = (char*)d_ws;
    auto alloc = [&](size_t bytes) -> char* {
        char* r = p;
        p += (bytes + 255) & ~size_t(255);
        return r;
    };
    int*   counts    = (int*)alloc((size_t)NN * 4);
    int*   offs      = (int*)alloc((size_t)(NN + 1) * 4);
    int*   cursor    = (int*)alloc((size_t)NN * 4);
    int*   blockSums = (int*)alloc(1024 * 4);
    float* dis       = (float*)alloc((size_t)NN * 4);
    int*   csr_src   = (int*)alloc((size_t)NE * 4);
    f16*   WT1       = (f16*)alloc((size_t)128 * 128 * 2);
    f16*   WT2       = (f16*)alloc((size_t)128 * 128 * 2);
    f16*   bufA      = (f16*)alloc((size_t)NN * F * 2);
    f16*   bufB      = (f16*)alloc((size_t)NN * F * 2);

    const int nscan = (NN + 1023) / 1024;

    hipMemsetAsync(counts, 0, (size_t)NN * 4, stream);
    count_edges<<<(NE + 255) / 256, 256, 0, stream>>>(ei, counts);
    compute_dis<<<(NN + 255) / 256, 256, 0, stream>>>(counts, dis);
    scan1<<<nscan, 1024, 0, stream>>>(counts, offs, blockSums, NN);
    scan2<<<1, 128, 0, stream>>>(blockSums, nscan);
    scan3<<<(NN + 1 + 255) / 256, 256, 0, stream>>>(offs, blockSums, cursor, NN);
    fill_csr<<<(NE + 255) / 256, 256, 0, stream>>>(ei, cursor, csr_src);
    prep_w<<<64, 256, 0, stream>>>(W1, W2, WT1, WT2);

    gemm_mfma<false><<<(NN + 127) / 128, 256, 0, stream>>>(X, WT1, dis, bufA, NN);
    aggregate16<<<(NN + 3) / 4, 256, 0, stream>>>(bufA, offs, csr_src, dis, b1, bufB, NN);
    gemm_mfma<true><<<(NN + 127) / 128, 256, 0, stream>>>(bufB, WT2, dis, bufA, NN);
    aggregate16<<<(NN + 3) / 4, 256, 0, stream>>>(bufA, offs, csr_src, dis, b2, bufB, NN);
    pool_linear<<<NG, 128, 0, stream>>>(bufB, batch, Wlin, blin, out, NN);
}

// Round 4
// 315.218 us; speedup vs baseline: 2.4950x; 1.4322x over previous
//
#include <hip/hip_runtime.h>
#include <hip/hip_bf16.h>
#include <hip/hip_fp16.h>

// GCN: x1 = relu(scatter(norm * (X@W1)[src] -> dst) + b1)
//      x2 = relu(scatter(norm * (x1@W2)[src] -> dst) + b2)
//      out = meanpool_by_graph(x2) @ Wlin + blin
// Factored norm: out[d] = dis[d]*(sum_{s in N(d)} h'[s] + h'[d]) + b,
// where h' = (X@W) row-scaled by dis (GEMM epilogue, fp16 stored).
// CSR built via 2-pass LDS-write-combined bucket sort (no scattered 4B writes).
constexpr int NN = 100000;   // nodes
constexpr int NE = 1600000;  // edges
constexpr int NG = 512;      // graphs
constexpr int F  = 128;      // feature dim (in == hidden)

constexpr int NB   = 392;    // buckets: node bucket = dst >> 8 (392*256 = 100352 >= NN)
constexpr int RCAP = 4608;   // per-bucket region capacity (Poisson(4082) + 8 sigma)
constexpr int CAP  = 32;     // LDS staging entries per bucket

typedef _Float16 f16;
typedef f16 f16x2 __attribute__((ext_vector_type(2)));
typedef f16 f16x4 __attribute__((ext_vector_type(4)));
typedef f16 f16x8 __attribute__((ext_vector_type(8)));
typedef float f32x4 __attribute__((ext_vector_type(4)));
typedef unsigned int u32;
typedef u32 u32x4a __attribute__((ext_vector_type(4), aligned(4)));  // 4B-aligned vec store

// ---------------- CSR build, pass 0: init per-bucket cursors ----------------
__global__ void init_cursors(int* __restrict__ gcur) {
    int b = blockIdx.x * blockDim.x + threadIdx.x;
    if (b < NB) gcur[b] = b * RCAP;
}

// ---------------- pass 1: bin edges by dst bucket, LDS write-combining ----------------
// 256 blocks x 256 threads; each block owns NE/256 = 6250 edges (25 rounds).
// Entry packed: (dst & 255) << 24 | src   (src < 2^17).
__global__ __launch_bounds__(256) void bin_edges(const int* __restrict__ ei,
                                                 int* __restrict__ gcur,
                                                 u32* __restrict__ binned) {
    __shared__ u32 stage[NB][CAP];   // 50 KB
    __shared__ int scnt[NB];
    for (int b = threadIdx.x; b < NB; b += 256) scnt[b] = 0;
    __syncthreads();
    const int per = NE / 256;        // 6250
    const int e0 = blockIdx.x * per;
    for (int r = 0; r < per; r += 256) {
        int k = r + threadIdx.x;
        if (k < per) {
            int e = e0 + k;
            int s = ei[e], d = ei[NE + e];
            int b = d >> 8;
            u32 v = ((u32)(d & 255) << 24) | (u32)s;
            int p = atomicAdd(&scnt[b], 1);
            if (p < CAP) stage[b][p] = v;   // overflow impossible in practice (P ~ 1e-18)
        }
        __syncthreads();
        // flush full groups of 16 (64 B aligned-ish coalesced writes)
        for (int b2 = threadIdx.x; b2 < NB; b2 += 256) {
            int n = scnt[b2];
            if (n >= 16) {
                int f = n & ~15;
                int base = atomicAdd(&gcur[b2], f);
                const u32x4a* st4 = (const u32x4a*)&stage[b2][0];
                u32x4a* out4 = (u32x4a*)&binned[base];
                for (int j = 0; j < (f >> 2); j++) out4[j] = st4[j];
                for (int j = 0; j < n - f; j++) stage[b2][j] = stage[b2][f + j];
                scnt[b2] = n - f;
            }
        }
        __syncthreads();
    }
    // final partial flush
    for (int b2 = threadIdx.x; b2 < NB; b2 += 256) {
        int n = scnt[b2];
        if (n > 0) {
            int base = atomicAdd(&gcur[b2], n);
            for (int j = 0; j < n; j++) binned[base + j] = stage[b2][j];
        }
    }
}

// ---------------- pass 1.5: scan bucket counts -> bucket bases ----------------
__global__ void scan_buckets(const int* __restrict__ gcur, int* __restrict__ bucketBase,
                             int* __restrict__ offs) {
    __shared__ int tmp[512];
    int t = threadIdx.x;
    int c = (t < NB) ? (gcur[t] - t * RCAP) : 0;
    tmp[t] = c;
    __syncthreads();
    for (int d = 1; d < 512; d <<= 1) {
        int x = (t >= d) ? tmp[t - d] : 0;
        __syncthreads();
        tmp[t] += x;
        __syncthreads();
    }
    if (t < NB) bucketBase[t] = tmp[t] - c;
    if (t == 0) offs[NN] = NE;
}

// ---------------- pass 2: per-bucket local CSR in LDS -> coalesced writeout ----------------
// One block per bucket (<= 4608 edges, 256 nodes). Also emits offs[] and dis[].
__global__ __launch_bounds__(256) void build_csr(const u32* __restrict__ binned,
                                                 const int* __restrict__ gcur,
                                                 const int* __restrict__ bucketBase,
                                                 int* __restrict__ offs,
                                                 float* __restrict__ dis,
                                                 int* __restrict__ csr_src) {
    __shared__ u32 ed[RCAP];     // 18.4 KB
    __shared__ u32 lcsr[RCAP];   // 18.4 KB
    __shared__ int hist[256];
    __shared__ int loff[256];
    __shared__ int lcur[256];
    const int b = blockIdx.x;
    int cnt = gcur[b] - b * RCAP;
    if (cnt > RCAP) cnt = RCAP;  // safety clamp
    const int gbase = bucketBase[b];
    const int t = threadIdx.x;
    hist[t] = 0;
    __syncthreads();
    for (int j = t; j < cnt; j += 256) {
        u32 v = binned[(size_t)b * RCAP + j];
        ed[j] = v;
        atomicAdd(&hist[v >> 24], 1);
    }
    __syncthreads();
    int h = hist[t];
    loff[t] = h;
    __syncthreads();
    for (int d = 1; d < 256; d <<= 1) {
        int x = (t >= d) ? loff[t - d] : 0;
        __syncthreads();
        loff[t] += x;
        __syncthreads();
    }
    int excl = loff[t] - h;
    lcur[t] = excl;
    int node = (b << 8) + t;
    if (node < NN) {
        offs[node] = gbase + excl;
        dis[node] = rsqrtf((float)(h + 1));   // +1 self-loop
    }
    __syncthreads();
    for (int j = t; j < cnt; j += 256) {
        u32 v = ed[j];
        int p = atomicAdd(&lcur[v >> 24], 1);
        lcsr[p] = v & 0x1FFFFu;
    }
    __syncthreads();
    for (int j = t; j < cnt; j += 256) csr_src[gbase + j] = (int)lcsr[j];
}

// ---------------- W prep: fp32 [k][n] -> fp16 transposed [n][k] ----------------
__global__ void prep_w(const float* __restrict__ W1, const float* __restrict__ W2,
                       f16* __restrict__ WT1, f16* __restrict__ WT2) {
    int idx = blockIdx.x * blockDim.x + threadIdx.x;
    if (idx < 128 * 128) {
        int n = idx >> 7, k = idx & 127;
        WT1[idx] = (f16)W1[k * 128 + n];
        WT2[idx] = (f16)W2[k * 128 + n];
    }
}

// ---------------- MFMA fp16 GEMM: H[M,128] = (X[M,128] @ W[128,128]) * dis[row] ----------------
template<bool IN_HALF>
__global__ __launch_bounds__(256) void gemm_mfma(const void* __restrict__ Xv,
                                                 const f16* __restrict__ WT,  // [n][k] fp16
                                                 const float* __restrict__ dis,
                                                 f16* __restrict__ H, int M) {
    __shared__ f16 sX[128 * 136];
    __shared__ f16 sW[128 * 136];
    const int tid = threadIdx.x;
    const int row0 = blockIdx.x * 128;
    {   // stage W^T: [n][k]
        const f16x8* Wg = (const f16x8*)WT;
        #pragma unroll
        for (int i = 0; i < 8; i++) {
            int idx = tid + 256 * i;
            int n = idx >> 4, kc = idx & 15;
            *(f16x8*)&sW[n * 136 + kc * 8] = Wg[idx];
        }
    }
    if (IN_HALF) {
        const f16x8* Xg = (const f16x8*)Xv;
        #pragma unroll
        for (int i = 0; i < 8; i++) {
            int idx = tid + 256 * i;
            int r = idx >> 4, kc = idx & 15;
            f16x8 v = {};
            if (row0 + r < M) v = Xg[(size_t)(row0 + r) * 16 + kc];
            *(f16x8*)&sX[r * 136 + kc * 8] = v;
        }
    } else {
        const float4* Xg = (const float4*)Xv;
        #pragma unroll
        for (int i = 0; i < 16; i++) {
            int idx = tid + 256 * i;
            int r = idx >> 5, c4 = idx & 31;
            float4 v = make_float4(0.f, 0.f, 0.f, 0.f);
            if (row0 + r < M) v = Xg[(size_t)(row0 + r) * 32 + c4];
            f16x4 hv = {(f16)v.x, (f16)v.y, (f16)v.z, (f16)v.w};
            *(f16x4*)&sX[r * 136 + c4 * 4] = hv;
        }
    }
    __syncthreads();

    const int wid = tid >> 6;
    const int lane = tid & 63;
    const int wrow = wid * 32;
    const int lr = lane & 15;
    const int lk = (lane >> 4) * 8;
    f32x4 acc[2][8] = {};
    #pragma unroll
    for (int ks = 0; ks < 4; ks++) {
        f16x8 a[2], b[8];
        #pragma unroll
        for (int mf = 0; mf < 2; mf++)
            a[mf] = *(const f16x8*)&sX[(wrow + mf * 16 + lr) * 136 + ks * 32 + lk];
        #pragma unroll
        for (int nf = 0; nf < 8; nf++)
            b[nf] = *(const f16x8*)&sW[(nf * 16 + lr) * 136 + ks * 32 + lk];
        #pragma unroll
        for (int mf = 0; mf < 2; mf++)
            #pragma unroll
            for (int nf = 0; nf < 8; nf++)
                acc[mf][nf] = __builtin_amdgcn_mfma_f32_16x16x32_f16(a[mf], b[nf], acc[mf][nf], 0, 0, 0);
    }
    // C layout: col = lane&15, row = (lane>>4)*4 + reg
    const int crow = (lane >> 4) * 4;
    #pragma unroll
    for (int mf = 0; mf < 2; mf++) {
        #pragma unroll
        for (int reg = 0; reg < 4; reg++) {
            int row = row0 + wrow + mf * 16 + crow + reg;
            if (row < M) {
                float sc = dis[row];
                #pragma unroll
                for (int nf = 0; nf < 8; nf++)
                    H[(size_t)row * 128 + nf * 16 + lr] = (f16)(acc[mf][nf][reg] * sc);
            }
        }
    }
}

// ---------------- per-node gather row-sum + scale + bias + relu (fp16 h') ----------------
__global__ __launch_bounds__(256) void aggregate16(const f16* __restrict__ h,
                                                   const int* __restrict__ offs,
                                                   const int* __restrict__ csr_src,
                                                   const float* __restrict__ dis,
                                                   const float* __restrict__ bias,
                                                   f16* __restrict__ out, int n) {
    int i = blockIdx.x * 4 + (threadIdx.x >> 6);
    if (i >= n) return;
    const int lane = threadIdx.x & 63;
    const int q = lane >> 4;      // quarter 0..3
    const int r = lane & 15;      // 16-byte chunk within row
    float acc[8] = {};
    if (q == 0) {  // self-loop
        f16x8 v = *(const f16x8*)(h + (size_t)i * F + r * 8);
        #pragma unroll
        for (int j = 0; j < 8; j++) acc[j] = (float)v[j];
    }
    const int s = offs[i], e = offs[i + 1];
    int t = s + q;
    for (; t + 4 < e; t += 8) {
        int sr0 = csr_src[t];
        int sr1 = csr_src[t + 4];
        f16x8 v0 = *(const f16x8*)(h + (size_t)sr0 * F + r * 8);
        f16x8 v1 = *(const f16x8*)(h + (size_t)sr1 * F + r * 8);
        #pragma unroll
        for (int j = 0; j < 8; j++) acc[j] += (float)v0[j] + (float)v1[j];
    }
    if (t < e) {
        int sr = csr_src[t];
        f16x8 v = *(const f16x8*)(h + (size_t)sr * F + r * 8);
        #pragma unroll
        for (int j = 0; j < 8; j++) acc[j] += (float)v[j];
    }
    #pragma unroll
    for (int j = 0; j < 8; j++) {
        acc[j] += __shfl_xor(acc[j], 16);
        acc[j] += __shfl_xor(acc[j], 32);
    }
    if (q == 0) {
        float di = dis[i];
        const float4* b4 = (const float4*)bias;
        float4 bb0 = b4[r * 2], bb1 = b4[r * 2 + 1];
        float bb[8] = {bb0.x, bb0.y, bb0.z, bb0.w, bb1.x, bb1.y, bb1.z, bb1.w};
        f16x8 o;
        #pragma unroll
        for (int j = 0; j < 8; j++) {
            float v = fmaf(acc[j], di, bb[j]);
            o[j] = (f16)(v > 0.f ? v : 0.f);
        }
        *(f16x8*)(out + (size_t)i * F + r * 8) = o;
    }
}

// ---------------- fused mean-pool (sorted batch, binary search) + linear ----------------
__global__ __launch_bounds__(128) void pool_linear(const f16* __restrict__ x,
                                                   const int* __restrict__ batch,
                                                   const float* __restrict__ Wlin,
                                                   const float* __restrict__ blin,
                                                   float* __restrict__ out, int n) {
    int g = blockIdx.x;
    int f = threadIdx.x;
    __shared__ int se[2];
    if (threadIdx.x < 2) {
        int target = g + threadIdx.x;
        int lo = 0, hi = n;
        while (lo < hi) {
            int mid = (lo + hi) >> 1;
            if (batch[mid] < target) lo = mid + 1; else hi = mid;
        }
        se[threadIdx.x] = lo;
    }
    __syncthreads();
    int s = se[0], e = se[1];
    float acc = 0.f;
    for (int i = s; i < e; i++) acc += (float)x[(size_t)i * F + f];
    float cnt = (float)((e - s) > 0 ? (e - s) : 1);
    float p = acc / cnt;
    float v0 = p * Wlin[f * 2 + 0];
    float v1 = p * Wlin[f * 2 + 1];
    #pragma unroll
    for (int o = 32; o > 0; o >>= 1) {
        v0 += __shfl_xor(v0, o);
        v1 += __shfl_xor(v1, o);
    }
    __shared__ float red[4];
    int wid = threadIdx.x >> 6;
    if ((threadIdx.x & 63) == 0) { red[wid * 2] = v0; red[wid * 2 + 1] = v1; }
    __syncthreads();
    if (threadIdx.x == 0) {
        out[g * 2 + 0] = red[0] + red[2] + blin[0];
        out[g * 2 + 1] = red[1] + red[3] + blin[1];
    }
}

extern "C" void kernel_launch(void* const* d_in, const int* in_sizes, int n_in,
                              void* d_out, int out_size, void* d_ws, size_t ws_size,
                              hipStream_t stream) {
    const float* X     = (const float*)d_in[0];
    const int*   ei    = (const int*)d_in[1];
    const int*   batch = (const int*)d_in[2];
    const float* W1    = (const float*)d_in[3];
    const float* b1    = (const float*)d_in[4];
    const float* W2    = (const float*)d_in[5];
    const float* b2    = (const float*)d_in[6];
    const float* Wlin  = (const float*)d_in[7];
    const float* blin  = (const float*)d_in[8];
    float* out = (float*)d_out;

    char* p = (char*)d_ws;
    auto alloc = [&](size_t bytes) -> char* {
        char* r = p;
        p += (bytes + 255) & ~size_t(255);
        return r;
    };
    int*   gcur       = (int*)alloc((size_t)NB * 4);
    int*   bucketBase = (int*)alloc((size_t)NB * 4);
    int*   offs       = (int*)alloc((size_t)(NN + 1) * 4);
    float* dis        = (float*)alloc((size_t)NN * 4);
    u32*   binned     = (u32*)alloc((size_t)NB * RCAP * 4);
    int*   csr_src    = (int*)alloc((size_t)NE * 4);
    f16*   WT1        = (f16*)alloc((size_t)128 * 128 * 2);
    f16*   WT2        = (f16*)alloc((size_t)128 * 128 * 2);
    f16*   bufA       = (f16*)alloc((size_t)NN * F * 2);
    f16*   bufB       = (f16*)alloc((size_t)NN * F * 2);

    init_cursors<<<2, 256, 0, stream>>>(gcur);
    bin_edges<<<256, 256, 0, stream>>>(ei, gcur, binned);
    scan_buckets<<<1, 512, 0, stream>>>(gcur, bucketBase, offs);
    build_csr<<<NB, 256, 0, stream>>>(binned, gcur, bucketBase, offs, dis, csr_src);
    prep_w<<<64, 256, 0, stream>>>(W1, W2, WT1, WT2);

    gemm_mfma<false><<<(NN + 127) / 128, 256, 0, stream>>>(X, WT1, dis, bufA, NN);
    aggregate16<<<(NN + 3) / 4, 256, 0, stream>>>(bufA, offs, csr_src, dis, b1, bufB, NN);
    gemm_mfma<true><<<(NN + 127) / 128, 256, 0, stream>>>(bufB, WT2, dis, bufA, NN);
    aggregate16<<<(NN + 3) / 4, 256, 0, stream>>>(bufA, offs, csr_src, dis, b2, bufB, NN);
    pool_linear<<<NG, 128, 0, stream>>>(bufB, batch, Wlin, blin, out, NN);
}

// Round 5
// 264.886 us; speedup vs baseline: 2.9690x; 1.1900x over previous
//
#include <hip/hip_runtime.h>
#include <hip/hip_bf16.h>
#include <hip/hip_fp16.h>

// GCN: x1 = relu(scatter(norm * (X@W1)[src] -> dst) + b1)
//      x2 = relu(scatter(norm * (x1@W2)[src] -> dst) + b2)
//      out = meanpool_by_graph(x2) @ Wlin + blin
// Factored norm: out[d] = dis[d]*(sum_{s in N(d)} h'[s] + h'[d]) + b,
// where h' = (X@W) row-scaled by dis (GEMM epilogue, fp16 stored).
// CSR built via 2-pass LDS-write-combined bucket sort (no scattered 4B writes).
// Pooling: 32-way parallel partial sums + tiny final reduce.
constexpr int NN = 100000;   // nodes
constexpr int NE = 1600000;  // edges
constexpr int NG = 512;      // graphs
constexpr int F  = 128;      // feature dim (in == hidden)

constexpr int NB   = 392;    // buckets: node bucket = dst >> 8 (392*256 = 100352 >= NN)
constexpr int RCAP = 4608;   // per-bucket region capacity (Poisson(4082) + 8 sigma)
constexpr int CAP  = 32;     // LDS staging entries per bucket
constexpr int NCH  = 8;      // pooling chunks per graph

typedef _Float16 f16;
typedef f16 f16x2 __attribute__((ext_vector_type(2)));
typedef f16 f16x4 __attribute__((ext_vector_type(4)));
typedef f16 f16x8 __attribute__((ext_vector_type(8)));
typedef float f32x4 __attribute__((ext_vector_type(4)));
typedef unsigned int u32;
typedef u32 u32x4a __attribute__((ext_vector_type(4), aligned(4)));  // 4B-aligned vec store

// ---------------- CSR build, pass 0: init per-bucket cursors ----------------
__global__ void init_cursors(int* __restrict__ gcur) {
    int b = blockIdx.x * blockDim.x + threadIdx.x;
    if (b < NB) gcur[b] = b * RCAP;
}

// ---------------- pass 1: bin edges by dst bucket, LDS write-combining ----------------
__global__ __launch_bounds__(256) void bin_edges(const int* __restrict__ ei,
                                                 int* __restrict__ gcur,
                                                 u32* __restrict__ binned) {
    __shared__ u32 stage[NB][CAP];   // 50 KB
    __shared__ int scnt[NB];
    for (int b = threadIdx.x; b < NB; b += 256) scnt[b] = 0;
    __syncthreads();
    const int per = NE / 256;        // 6250
    const int e0 = blockIdx.x * per;
    for (int r = 0; r < per; r += 256) {
        int k = r + threadIdx.x;
        if (k < per) {
            int e = e0 + k;
            int s = ei[e], d = ei[NE + e];
            int b = d >> 8;
            u32 v = ((u32)(d & 255) << 24) | (u32)s;
            int p = atomicAdd(&scnt[b], 1);
            if (p < CAP) stage[b][p] = v;   // overflow impossible in practice (P ~ 1e-18)
        }
        __syncthreads();
        for (int b2 = threadIdx.x; b2 < NB; b2 += 256) {
            int n = scnt[b2];
            if (n >= 16) {
                int f = n & ~15;
                int base = atomicAdd(&gcur[b2], f);
                const u32x4a* st4 = (const u32x4a*)&stage[b2][0];
                u32x4a* out4 = (u32x4a*)&binned[base];
                for (int j = 0; j < (f >> 2); j++) out4[j] = st4[j];
                for (int j = 0; j < n - f; j++) stage[b2][j] = stage[b2][f + j];
                scnt[b2] = n - f;
            }
        }
        __syncthreads();
    }
    for (int b2 = threadIdx.x; b2 < NB; b2 += 256) {
        int n = scnt[b2];
        if (n > 0) {
            int base = atomicAdd(&gcur[b2], n);
            for (int j = 0; j < n; j++) binned[base + j] = stage[b2][j];
        }
    }
}

// ---------------- pass 1.5: scan bucket counts -> bucket bases ----------------
__global__ void scan_buckets(const int* __restrict__ gcur, int* __restrict__ bucketBase,
                             int* __restrict__ offs) {
    __shared__ int tmp[512];
    int t = threadIdx.x;
    int c = (t < NB) ? (gcur[t] - t * RCAP) : 0;
    tmp[t] = c;
    __syncthreads();
    for (int d = 1; d < 512; d <<= 1) {
        int x = (t >= d) ? tmp[t - d] : 0;
        __syncthreads();
        tmp[t] += x;
        __syncthreads();
    }
    if (t < NB) bucketBase[t] = tmp[t] - c;
    if (t == 0) offs[NN] = NE;
}

// ---------------- pass 2: per-bucket local CSR in LDS -> coalesced writeout ----------------
__global__ __launch_bounds__(256) void build_csr(const u32* __restrict__ binned,
                                                 const int* __restrict__ gcur,
                                                 const int* __restrict__ bucketBase,
                                                 int* __restrict__ offs,
                                                 float* __restrict__ dis,
                                                 int* __restrict__ csr_src) {
    __shared__ u32 ed[RCAP];     // 18.4 KB
    __shared__ u32 lcsr[RCAP];   // 18.4 KB
    __shared__ int hist[256];
    __shared__ int loff[256];
    __shared__ int lcur[256];
    const int b = blockIdx.x;
    int cnt = gcur[b] - b * RCAP;
    if (cnt > RCAP) cnt = RCAP;  // safety clamp
    const int gbase = bucketBase[b];
    const int t = threadIdx.x;
    hist[t] = 0;
    __syncthreads();
    for (int j = t; j < cnt; j += 256) {
        u32 v = binned[(size_t)b * RCAP + j];
        ed[j] = v;
        atomicAdd(&hist[v >> 24], 1);
    }
    __syncthreads();
    int h = hist[t];
    loff[t] = h;
    __syncthreads();
    for (int d = 1; d < 256; d <<= 1) {
        int x = (t >= d) ? loff[t - d] : 0;
        __syncthreads();
        loff[t] += x;
        __syncthreads();
    }
    int excl = loff[t] - h;
    lcur[t] = excl;
    int node = (b << 8) + t;
    if (node < NN) {
        offs[node] = gbase + excl;
        dis[node] = rsqrtf((float)(h + 1));   // +1 self-loop
    }
    __syncthreads();
    for (int j = t; j < cnt; j += 256) {
        u32 v = ed[j];
        int p = atomicAdd(&lcur[v >> 24], 1);
        lcsr[p] = v & 0x1FFFFu;
    }
    __syncthreads();
    for (int j = t; j < cnt; j += 256) csr_src[gbase + j] = (int)lcsr[j];
}

// ---------------- W prep: fp32 [k][n] -> fp16 transposed [n][k] ----------------
__global__ void prep_w(const float* __restrict__ W1, const float* __restrict__ W2,
                       f16* __restrict__ WT1, f16* __restrict__ WT2) {
    int idx = blockIdx.x * blockDim.x + threadIdx.x;
    if (idx < 128 * 128) {
        int n = idx >> 7, k = idx & 127;
        WT1[idx] = (f16)W1[k * 128 + n];
        WT2[idx] = (f16)W2[k * 128 + n];
    }
}

// ---------------- MFMA fp16 GEMM: H[M,128] = (X[M,128] @ W[128,128]) * dis[row] ----------------
template<bool IN_HALF>
__global__ __launch_bounds__(256) void gemm_mfma(const void* __restrict__ Xv,
                                                 const f16* __restrict__ WT,  // [n][k] fp16
                                                 const float* __restrict__ dis,
                                                 f16* __restrict__ H, int M) {
    __shared__ f16 sX[128 * 136];
    __shared__ f16 sW[128 * 136];
    const int tid = threadIdx.x;
    const int row0 = blockIdx.x * 128;
    {   // stage W^T: [n][k]
        const f16x8* Wg = (const f16x8*)WT;
        #pragma unroll
        for (int i = 0; i < 8; i++) {
            int idx = tid + 256 * i;
            int n = idx >> 4, kc = idx & 15;
            *(f16x8*)&sW[n * 136 + kc * 8] = Wg[idx];
        }
    }
    if (IN_HALF) {
        const f16x8* Xg = (const f16x8*)Xv;
        #pragma unroll
        for (int i = 0; i < 8; i++) {
            int idx = tid + 256 * i;
            int r = idx >> 4, kc = idx & 15;
            f16x8 v = {};
            if (row0 + r < M) v = Xg[(size_t)(row0 + r) * 16 + kc];
            *(f16x8*)&sX[r * 136 + kc * 8] = v;
        }
    } else {
        const float4* Xg = (const float4*)Xv;
        #pragma unroll
        for (int i = 0; i < 16; i++) {
            int idx = tid + 256 * i;
            int r = idx >> 5, c4 = idx & 31;
            float4 v = make_float4(0.f, 0.f, 0.f, 0.f);
            if (row0 + r < M) v = Xg[(size_t)(row0 + r) * 32 + c4];
            f16x4 hv = {(f16)v.x, (f16)v.y, (f16)v.z, (f16)v.w};
            *(f16x4*)&sX[r * 136 + c4 * 4] = hv;
        }
    }
    __syncthreads();

    const int wid = tid >> 6;
    const int lane = tid & 63;
    const int wrow = wid * 32;
    const int lr = lane & 15;
    const int lk = (lane >> 4) * 8;
    f32x4 acc[2][8] = {};
    #pragma unroll
    for (int ks = 0; ks < 4; ks++) {
        f16x8 a[2], b[8];
        #pragma unroll
        for (int mf = 0; mf < 2; mf++)
            a[mf] = *(const f16x8*)&sX[(wrow + mf * 16 + lr) * 136 + ks * 32 + lk];
        #pragma unroll
        for (int nf = 0; nf < 8; nf++)
            b[nf] = *(const f16x8*)&sW[(nf * 16 + lr) * 136 + ks * 32 + lk];
        #pragma unroll
        for (int mf = 0; mf < 2; mf++)
            #pragma unroll
            for (int nf = 0; nf < 8; nf++)
                acc[mf][nf] = __builtin_amdgcn_mfma_f32_16x16x32_f16(a[mf], b[nf], acc[mf][nf], 0, 0, 0);
    }
    // C layout: col = lane&15, row = (lane>>4)*4 + reg
    const int crow = (lane >> 4) * 4;
    #pragma unroll
    for (int mf = 0; mf < 2; mf++) {
        #pragma unroll
        for (int reg = 0; reg < 4; reg++) {
            int row = row0 + wrow + mf * 16 + crow + reg;
            if (row < M) {
                float sc = dis[row];
                #pragma unroll
                for (int nf = 0; nf < 8; nf++)
                    H[(size_t)row * 128 + nf * 16 + lr] = (f16)(acc[mf][nf][reg] * sc);
            }
        }
    }
}

// ---------------- per-node gather row-sum + scale + bias + relu (fp16 h') ----------------
__global__ __launch_bounds__(256) void aggregate16(const f16* __restrict__ h,
                                                   const int* __restrict__ offs,
                                                   const int* __restrict__ csr_src,
                                                   const float* __restrict__ dis,
                                                   const float* __restrict__ bias,
                                                   f16* __restrict__ out, int n) {
    int i = blockIdx.x * 4 + (threadIdx.x >> 6);
    if (i >= n) return;
    const int lane = threadIdx.x & 63;
    const int q = lane >> 4;      // quarter 0..3
    const int r = lane & 15;      // 16-byte chunk within row
    float acc[8] = {};
    if (q == 0) {  // self-loop
        f16x8 v = *(const f16x8*)(h + (size_t)i * F + r * 8);
        #pragma unroll
        for (int j = 0; j < 8; j++) acc[j] = (float)v[j];
    }
    const int s = offs[i], e = offs[i + 1];
    int t = s + q;
    for (; t + 4 < e; t += 8) {
        int sr0 = csr_src[t];
        int sr1 = csr_src[t + 4];
        f16x8 v0 = *(const f16x8*)(h + (size_t)sr0 * F + r * 8);
        f16x8 v1 = *(const f16x8*)(h + (size_t)sr1 * F + r * 8);
        #pragma unroll
        for (int j = 0; j < 8; j++) acc[j] += (float)v0[j] + (float)v1[j];
    }
    if (t < e) {
        int sr = csr_src[t];
        f16x8 v = *(const f16x8*)(h + (size_t)sr * F + r * 8);
        #pragma unroll
        for (int j = 0; j < 8; j++) acc[j] += (float)v[j];
    }
    #pragma unroll
    for (int j = 0; j < 8; j++) {
        acc[j] += __shfl_xor(acc[j], 16);
        acc[j] += __shfl_xor(acc[j], 32);
    }
    if (q == 0) {
        float di = dis[i];
        const float4* b4 = (const float4*)bias;
        float4 bb0 = b4[r * 2], bb1 = b4[r * 2 + 1];
        float bb[8] = {bb0.x, bb0.y, bb0.z, bb0.w, bb1.x, bb1.y, bb1.z, bb1.w};
        f16x8 o;
        #pragma unroll
        for (int j = 0; j < 8; j++) {
            float v = fmaf(acc[j], di, bb[j]);
            o[j] = (f16)(v > 0.f ? v : 0.f);
        }
        *(f16x8*)(out + (size_t)i * F + r * 8) = o;
    }
}

// ---------------- pooling stage 1: 32-way parallel partial sums ----------------
// grid (NG, NCH), block 256 = 4 waves. Wave-slot k = blockIdx.y*4 + wid sums
// rows s+k, s+k+32, ... of graph g; lane reads f16x2 (full 256 B row / wave).
__global__ __launch_bounds__(256) void pool_partial(const f16* __restrict__ x,
                                                    const int* __restrict__ batch,
                                                    float* __restrict__ partial, int n) {
    int g = blockIdx.x;
    __shared__ int se[2];
    if (threadIdx.x < 2) {
        int target = g + threadIdx.x;
        int lo = 0, hi = n;
        while (lo < hi) {
            int mid = (lo + hi) >> 1;
            if (batch[mid] < target) lo = mid + 1; else hi = mid;
        }
        se[threadIdx.x] = lo;
    }
    __syncthreads();
    int s = se[0], e = se[1];
    int wid = threadIdx.x >> 6, lane = threadIdx.x & 63;
    int slot = blockIdx.y * 4 + wid;  // 0..31
    float a0 = 0.f, a1 = 0.f;
    const f16x2* x2 = (const f16x2*)x;
    for (int i = s + slot; i < e; i += 4 * NCH) {
        f16x2 v = x2[(size_t)i * 64 + lane];
        a0 += (float)v[0];
        a1 += (float)v[1];
    }
    __shared__ float red[4][128];
    red[wid][lane * 2] = a0;
    red[wid][lane * 2 + 1] = a1;
    __syncthreads();
    if (wid == 0) {
        float s0 = red[0][lane * 2] + red[1][lane * 2] + red[2][lane * 2] + red[3][lane * 2];
        float s1 = red[0][lane * 2 + 1] + red[1][lane * 2 + 1] + red[2][lane * 2 + 1] + red[3][lane * 2 + 1];
        float2* pp = (float2*)&partial[((size_t)g * NCH + blockIdx.y) * F];
        pp[lane] = make_float2(s0, s1);
    }
}

// ---------------- pooling stage 2: final reduce + linear head ----------------
__global__ __launch_bounds__(128) void pool_final(const float* __restrict__ partial,
                                                  const int* __restrict__ batch,
                                                  const float* __restrict__ Wlin,
                                                  const float* __restrict__ blin,
                                                  float* __restrict__ out, int n) {
    int g = blockIdx.x;
    int f = threadIdx.x;
    __shared__ int se[2];
    if (threadIdx.x < 2) {
        int target = g + threadIdx.x;
        int lo = 0, hi = n;
        while (lo < hi) {
            int mid = (lo + hi) >> 1;
            if (batch[mid] < target) lo = mid + 1; else hi = mid;
        }
        se[threadIdx.x] = lo;
    }
    __syncthreads();
    int s = se[0], e = se[1];
    float acc = 0.f;
    #pragma unroll
    for (int c = 0; c < NCH; c++) acc += partial[((size_t)g * NCH + c) * F + f];
    float cnt = (float)((e - s) > 0 ? (e - s) : 1);
    float p = acc / cnt;
    float v0 = p * Wlin[f * 2 + 0];
    float v1 = p * Wlin[f * 2 + 1];
    #pragma unroll
    for (int o = 32; o > 0; o >>= 1) {
        v0 += __shfl_xor(v0, o);
        v1 += __shfl_xor(v1, o);
    }
    __shared__ float red[4];
    int wid = threadIdx.x >> 6;
    if ((threadIdx.x & 63) == 0) { red[wid * 2] = v0; red[wid * 2 + 1] = v1; }
    __syncthreads();
    if (threadIdx.x == 0) {
        out[g * 2 + 0] = red[0] + red[2] + blin[0];
        out[g * 2 + 1] = red[1] + red[3] + blin[1];
    }
}

extern "C" void kernel_launch(void* const* d_in, const int* in_sizes, int n_in,
                              void* d_out, int out_size, void* d_ws, size_t ws_size,
                              hipStream_t stream) {
    const float* X     = (const float*)d_in[0];
    const int*   ei    = (const int*)d_in[1];
    const int*   batch = (const int*)d_in[2];
    const float* W1    = (const float*)d_in[3];
    const float* b1    = (const float*)d_in[4];
    const float* W2    = (const float*)d_in[5];
    const float* b2    = (const float*)d_in[6];
    const float* Wlin  = (const float*)d_in[7];
    const float* blin  = (const float*)d_in[8];
    float* out = (float*)d_out;

    char* p = (char*)d_ws;
    auto alloc = [&](size_t bytes) -> char* {
        char* r = p;
        p += (bytes + 255) & ~size_t(255);
        return r;
    };
    int*   gcur       = (int*)alloc((size_t)NB * 4);
    int*   bucketBase = (int*)alloc((size_t)NB * 4);
    int*   offs       = (int*)alloc((size_t)(NN + 1) * 4);
    float* dis        = (float*)alloc((size_t)NN * 4);
    u32*   binned     = (u32*)alloc((size_t)NB * RCAP * 4);
    int*   csr_src    = (int*)alloc((size_t)NE * 4);
    f16*   WT1        = (f16*)alloc((size_t)128 * 128 * 2);
    f16*   WT2        = (f16*)alloc((size_t)128 * 128 * 2);
    f16*   bufA       = (f16*)alloc((size_t)NN * F * 2);
    f16*   bufB       = (f16*)alloc((size_t)NN * F * 2);
    float* partial    = (float*)alloc((size_t)NG * NCH * F * 4);

    init_cursors<<<2, 256, 0, stream>>>(gcur);
    bin_edges<<<256, 256, 0, stream>>>(ei, gcur, binned);
    scan_buckets<<<1, 512, 0, stream>>>(gcur, bucketBase, offs);
    build_csr<<<NB, 256, 0, stream>>>(binned, gcur, bucketBase, offs, dis, csr_src);
    prep_w<<<64, 256, 0, stream>>>(W1, W2, WT1, WT2);

    gemm_mfma<false><<<(NN + 127) / 128, 256, 0, stream>>>(X, WT1, dis, bufA, NN);
    aggregate16<<<(NN + 3) / 4, 256, 0, stream>>>(bufA, offs, csr_src, dis, b1, bufB, NN);
    gemm_mfma<true><<<(NN + 127) / 128, 256, 0, stream>>>(bufB, WT2, dis, bufA, NN);
    aggregate16<<<(NN + 3) / 4, 256, 0, stream>>>(bufA, offs, csr_src, dis, b2, bufB, NN);
    pool_partial<<<dim3(NG, NCH), 256, 0, stream>>>(bufB, batch, partial, NN);
    pool_final<<<NG, 128, 0, stream>>>(partial, batch, Wlin, blin, out, NN);
}